// Round 2
// baseline (1394.082 us; speedup 1.0000x reference)
//
#include <hip/hip_runtime.h>
#include <cstdint>

#define AS1 __attribute__((address_space(1)))
#define AS3 __attribute__((address_space(3)))

typedef __bf16 bf16x8 __attribute__((ext_vector_type(8)));
typedef float f32x4 __attribute__((ext_vector_type(4)));

__device__ __forceinline__ unsigned short f2bf(float f) {
  unsigned u = __float_as_uint(f);
  u += 0x7FFFu + ((u >> 16) & 1u);   // RNE
  return (unsigned short)(u >> 16);
}
__device__ __forceinline__ float bflo(unsigned u) { return __uint_as_float(u << 16); }
__device__ __forceinline__ float bfhi(unsigned u) { return __uint_as_float(u & 0xFFFF0000u); }

__device__ __forceinline__ void unpack8(uint4 r, float* f) {
  f[0] = bflo(r.x); f[1] = bfhi(r.x);
  f[2] = bflo(r.y); f[3] = bfhi(r.y);
  f[4] = bflo(r.z); f[5] = bfhi(r.z);
  f[6] = bflo(r.w); f[7] = bfhi(r.w);
}

// ---------------- fp32 -> bf16 convert (8 elems/thread) ----------------
__global__ void k_f32_to_bf16(const float* __restrict__ in,
                              unsigned short* __restrict__ out, long n8) {
  long i = (long)blockIdx.x * blockDim.x + threadIdx.x;
  if (i >= n8) return;
  const float4* p = (const float4*)in + i * 2;
  float4 a = p[0], b = p[1];
  uint4 o;
  o.x = (unsigned)f2bf(a.x) | ((unsigned)f2bf(a.y) << 16);
  o.y = (unsigned)f2bf(a.z) | ((unsigned)f2bf(a.w) << 16);
  o.z = (unsigned)f2bf(b.x) | ((unsigned)f2bf(b.y) << 16);
  o.w = (unsigned)f2bf(b.z) | ((unsigned)f2bf(b.w) << 16);
  *((uint4*)out + i) = o;
}

// ------------- transpose + convert: out[c*R + r] = bf16(in[r*C + c]) -------------
__global__ void k_transpose_bf16(const float* __restrict__ in,
                                 unsigned short* __restrict__ out, int R, int C) {
  __shared__ float tile[32][33];
  int c0 = blockIdx.x * 32, r0 = blockIdx.y * 32;
  int tx = threadIdx.x & 31, ty = threadIdx.x >> 5;  // 256 threads = 32x8
  #pragma unroll
  for (int i = ty; i < 32; i += 8) tile[i][tx] = in[(long)(r0 + i) * C + c0 + tx];
  __syncthreads();
  #pragma unroll
  for (int i = ty; i < 32; i += 8) out[(long)(c0 + i) * R + r0 + tx] = f2bf(tile[tx][i]);
}

// out_w (H=16,F=1024,Dh=64) -> outw_bt[c=h*64+d][f] bf16 (1024x1024)
__global__ void k_transpose_outw(const float* __restrict__ in,
                                 unsigned short* __restrict__ out) {
  __shared__ float tile[32][33];
  int d0 = blockIdx.x * 32, f0 = blockIdx.y * 32, h = blockIdx.z;
  int tx = threadIdx.x & 31, ty = threadIdx.x >> 5;
  #pragma unroll
  for (int i = ty; i < 32; i += 8)
    tile[i][tx] = in[((long)h * 1024 + f0 + i) * 64 + d0 + tx];
  __syncthreads();
  #pragma unroll
  for (int i = ty; i < 32; i += 8)
    out[((long)h * 64 + d0 + i) * 1024 + f0 + tx] = f2bf(tile[tx][i]);
}

// ---------------- m97-structure bf16 GEMM, 128x128 tile, BK=64, 4 waves ----------------
enum { EPI_VIS = 0, EPI_QW, EPI_SELF, EPI_Q, EPI_K, EPI_KG };

template <int EPI>
__global__ __launch_bounds__(256) void k_gemm(
    const unsigned short* __restrict__ A, const unsigned short* __restrict__ Bt,
    int M, int K,
    const float* __restrict__ bias,
    const float* __restrict__ mask, const float* __restrict__ QW,
    float* __restrict__ outf, unsigned short* __restrict__ outb,
    unsigned short* __restrict__ ngf) {
  (void)M;
  __shared__ __align__(16) unsigned short As[128 * 64];
  __shared__ __align__(16) unsigned short Bs[128 * 64];
  const int t = threadIdx.x;
  const int l = t & 63, w = t >> 6;
  const int wm = w >> 1, wn = w & 1;
  const long bm0 = (long)blockIdx.y * 128, bn0 = (long)blockIdx.x * 128;

  f32x4 acc[4][4];
  #pragma unroll
  for (int i = 0; i < 4; ++i)
    #pragma unroll
    for (int j = 0; j < 4; ++j) acc[i][j] = (f32x4){0.f, 0.f, 0.f, 0.f};

  const int lrow = l & 15;
  const int lkbase = (l >> 4) * 8;

  for (int k0 = 0; k0 < K; k0 += 64) {
    #pragma unroll
    for (int i = 0; i < 4; ++i) {
      int c = i * 256 + t;
      int row = c >> 3, cc = (c & 7) << 3;
      const unsigned short* ga = A + (bm0 + row) * (long)K + k0 + cc;
      const unsigned short* gb = Bt + (bn0 + row) * (long)K + k0 + cc;
      int ldsoff = __builtin_amdgcn_readfirstlane((i * 256 + w * 64) * 8);
      __builtin_amdgcn_global_load_lds((AS1 void*)ga, (AS3 void*)(As + ldsoff), 16, 0, 0);
      __builtin_amdgcn_global_load_lds((AS1 void*)gb, (AS3 void*)(Bs + ldsoff), 16, 0, 0);
    }
    __syncthreads();
    #pragma unroll
    for (int kk = 0; kk < 2; ++kk) {
      bf16x8 af[4], bfr[4];
      const int lk = kk * 32 + lkbase;
      #pragma unroll
      for (int mf = 0; mf < 4; ++mf)
        af[mf] = *(const bf16x8*)(As + (wm * 64 + mf * 16 + lrow) * 64 + lk);
      #pragma unroll
      for (int nf = 0; nf < 4; ++nf)
        bfr[nf] = *(const bf16x8*)(Bs + (wn * 64 + nf * 16 + lrow) * 64 + lk);
      #pragma unroll
      for (int mf = 0; mf < 4; ++mf)
        #pragma unroll
        for (int nf = 0; nf < 4; ++nf)
          acc[mf][nf] = __builtin_amdgcn_mfma_f32_16x16x32_bf16(af[mf], bfr[nf],
                                                                acc[mf][nf], 0, 0, 0);
    }
    __syncthreads();
  }

  // epilogue: C/D layout col = lane&15, row = (lane>>4)*4 + reg
  #pragma unroll
  for (int mf = 0; mf < 4; ++mf) {
    #pragma unroll
    for (int r = 0; r < 4; ++r) {
      long row = bm0 + wm * 64 + mf * 16 + ((l >> 4) << 2) + r;
      #pragma unroll
      for (int nf = 0; nf < 4; ++nf) {
        long col = bn0 + wn * 64 + nf * 16 + (l & 15);
        float x = acc[mf][nf][r];
        long idx = row * 1024 + col;
        if (EPI == EPI_VIS) {
          x += bias[col];
          x = fmaxf(x, 0.f);
          outb[idx] = f2bf(x);
        } else if (EPI == EPI_QW) {
          outf[idx] = x;
        } else if (EPI == EPI_SELF) {
          int b = (int)(row / 36), n = (int)(row % 36);
          x += bias[col] + mask[row] * QW[(long)b * 1024 + col];
          outb[idx] = f2bf(x);
          if (n < 20) ngf[((long)b * 20 + n) * 1024 + col] = f2bf(x);
        } else if (EPI == EPI_Q) {
          x += bias[col];
          outb[idx] = f2bf(x);
        } else if (EPI == EPI_K) {
          x += bias[col];
          outb[idx] = f2bf(x);
        } else {  // EPI_KG
          outb[idx] = f2bf(x);
        }
      }
    }
  }
}

// ---------------- row mask from vis_bf: any nonzero? (vis >= 0 after relu) ----------------
__global__ void k_mask(const unsigned short* __restrict__ vis, float* __restrict__ mask) {
  int row = blockIdx.x * 4 + (threadIdx.x >> 6);
  int l = threadIdx.x & 63;
  const uint4* vr = (const uint4*)(vis + (long)row * 1024);
  unsigned s = 0;
  #pragma unroll
  for (int i = 0; i < 2; ++i) {
    uint4 v = vr[l + i * 64];
    s |= v.x | v.y | v.z | v.w;
  }
  #pragma unroll
  for (int st = 1; st < 64; st <<= 1) s |= __shfl_xor(s, st);
  if (l == 0) mask[row] = (s != 0) ? 1.f : 0.f;
}

// ------- pos_logit[b,n,m,h] = log(max(relu(pos_emb[b,n,m,:]·pos_w[:,h]+pos_b[h]),1e-6)) -------
__global__ __launch_bounds__(256) void k_poslogit(const float* __restrict__ pos_emb,
                                                  const float* __restrict__ pos_w,
                                                  const float* __restrict__ pos_b,
                                                  float* __restrict__ plog) {
  __shared__ float wsm[64 * 16];
  __shared__ float bsm[16];
  int t = threadIdx.x;
  for (int i = t; i < 1024; i += 256) wsm[i] = pos_w[i];
  if (t < 16) bsm[t] = pos_b[t];
  __syncthreads();
  long row = (long)blockIdx.x * 16 + (t >> 4);
  int h = t & 15;
  const float4* pr = (const float4*)(pos_emb + row * 64);
  float acc = bsm[h];
  #pragma unroll
  for (int i = 0; i < 16; ++i) {
    float4 v = pr[i];
    acc += v.x * wsm[(i * 4 + 0) * 16 + h];
    acc += v.y * wsm[(i * 4 + 1) * 16 + h];
    acc += v.z * wsm[(i * 4 + 2) * 16 + h];
    acc += v.w * wsm[(i * 4 + 3) * 16 + h];
  }
  acc = fmaxf(acc, 1e-6f);
  plog[row * 16 + h] = __logf(acc);
}

// ------- fused attention + neighbor + final residual -------
// Block per b (512 blocks, 576 threads = 9 waves). Phase 1: thread t owns
// pair (h = t/36, n = t%36): aff[20] in regs from K in LDS (broadcast reads),
// per-thread softmax (no cross-lane!). Phase 2: KG staged into reused K region,
// coalesced float4 outputs: out = vis + relu(self + attn@KG + out_b).
// LDS: [0,20480) ushort = K, then KG (reused); [20480, 32000) = attn (bf16, stride 20).
__global__ __launch_bounds__(576, 5) void k_attn(
    const unsigned short* __restrict__ qb, const unsigned short* __restrict__ kb,
    const unsigned short* __restrict__ kgb, const float* __restrict__ plog,
    const unsigned short* __restrict__ selfb, const unsigned short* __restrict__ visb,
    const float* __restrict__ outbias, float* __restrict__ out) {
  __shared__ __align__(16) unsigned short lds[32000];  // 64000 B
  const int t = threadIdx.x;
  const int b = blockIdx.x;
  const int w = t >> 6;

  // ---- stage K (40960 B) into lds[0:20480) with waves 0..7 (full waves) ----
  if (w < 8) {
    const unsigned short* srcK = kb + (long)b * 20480;
    #pragma unroll
    for (int k = 0; k < 5; ++k) {
      int chunk = k * 512 + t;  // t < 512 here
      int ldsoff = __builtin_amdgcn_readfirstlane((k * 512 + w * 64) * 16);
      __builtin_amdgcn_global_load_lds((AS1 void*)(srcK + chunk * 8),
                                       (AS3 void*)((char*)lds + ldsoff), 16, 0, 0);
    }
  }

  const int h = t / 36, n = t - h * 36;
  const long qrow = (long)b * 36 + n;
  const unsigned short* qp = qb + (qrow << 10) + h * 64;

  float aff[20];
  #pragma unroll
  for (int m = 0; m < 20; ++m) aff[m] = 0.f;

  __syncthreads();  // K staged (barrier drains vmcnt)

  // ---- phase 1: aff[m] = q . K[m], d-chunked, K broadcast from LDS ----
  const int kbase = h * 64;
  #pragma unroll
  for (int d0 = 0; d0 < 8; ++d0) {
    uint4 qraw = *(const uint4*)(qp + d0 * 8);
    float qf[8];
    unpack8(qraw, qf);
    #pragma unroll
    for (int m = 0; m < 20; ++m) {
      uint4 kraw = *(const uint4*)(lds + m * 1024 + kbase + d0 * 8);
      float kf[8];
      unpack8(kraw, kf);
      #pragma unroll
      for (int i = 0; i < 8; ++i) aff[m] += qf[i] * kf[i];
    }
  }

  __syncthreads();  // all K reads done before KG overwrites the region

  // ---- stage KG into lds[0:20480) (overlaps with softmax below) ----
  if (w < 8) {
    const unsigned short* srcG = kgb + (long)b * 20480;
    #pragma unroll
    for (int k = 0; k < 5; ++k) {
      int chunk = k * 512 + t;
      int ldsoff = __builtin_amdgcn_readfirstlane((k * 512 + w * 64) * 16);
      __builtin_amdgcn_global_load_lds((AS1 void*)(srcG + chunk * 8),
                                       (AS3 void*)((char*)lds + ldsoff), 16, 0, 0);
    }
  }

  // ---- per-thread softmax (register-only) ----
  {
    const float* pl = plog + ((qrow * 20) << 4) + h;
    #pragma unroll
    for (int m = 0; m < 20; ++m) aff[m] = aff[m] * 0.125f + pl[m * 16];
    float amax = aff[0];
    #pragma unroll
    for (int m = 1; m < 20; ++m) amax = fmaxf(amax, aff[m]);
    float s = 0.f;
    #pragma unroll
    for (int m = 0; m < 20; ++m) {
      aff[m] = __expf(aff[m] - amax);
      s += aff[m];
    }
    float inv = 1.f / s;
    unsigned short* ap = lds + 20480 + t * 20;
    #pragma unroll
    for (int m = 0; m < 20; m += 2) {
      unsigned lo = f2bf(aff[m] * inv), hi = f2bf(aff[m + 1] * inv);
      *(unsigned*)(ap + m) = lo | (hi << 16);
    }
  }

  __syncthreads();  // KG staged + attn written

  // ---- phase 2: coalesced output, 16 float4 per thread ----
  const long obase = (long)b * 36864;
  #pragma unroll
  for (int j = 0; j < 16; ++j) {
    int f = (j * 576 + t) << 2;
    int n2 = f >> 10;
    int hd = f & 1023;
    const unsigned short* ap = lds + 20480 + ((hd >> 6) * 36 + n2) * 20;
    unsigned av[10];
    #pragma unroll
    for (int i = 0; i < 5; ++i) {
      uint2 v = *(const uint2*)(ap + i * 4);
      av[2 * i] = v.x;
      av[2 * i + 1] = v.y;
    }
    f32x4 acc = (f32x4){0.f, 0.f, 0.f, 0.f};
    #pragma unroll
    for (int m = 0; m < 20; m += 2) {
      unsigned apair = av[m >> 1];
      float a0 = bflo(apair), a1 = bfhi(apair);
      const unsigned short* g0 = lds + m * 1024 + hd;
      uint2 r0 = *(const uint2*)g0;
      uint2 r1 = *(const uint2*)(g0 + 1024);
      acc[0] += a0 * bflo(r0.x);
      acc[1] += a0 * bfhi(r0.x);
      acc[2] += a0 * bflo(r0.y);
      acc[3] += a0 * bfhi(r0.y);
      acc[0] += a1 * bflo(r1.x);
      acc[1] += a1 * bfhi(r1.x);
      acc[2] += a1 * bflo(r1.y);
      acc[3] += a1 * bfhi(r1.y);
    }
    long gidx = obase + f;
    uint2 sv = *(const uint2*)(selfb + gidx);
    uint2 vv = *(const uint2*)(visb + gidx);
    float4 bi = *(const float4*)(outbias + hd);
    float4 o;
    o.x = bflo(vv.x) + fmaxf(bflo(sv.x) + acc[0] + bi.x, 0.f);
    o.y = bfhi(vv.x) + fmaxf(bfhi(sv.x) + acc[1] + bi.y, 0.f);
    o.z = bflo(vv.y) + fmaxf(bflo(sv.y) + acc[2] + bi.z, 0.f);
    o.w = bfhi(vv.y) + fmaxf(bfhi(sv.y) + acc[3] + bi.w, 0.f);
    *(float4*)(out + gidx) = o;
  }
}

extern "C" void kernel_launch(void* const* d_in, const int* in_sizes, int n_in,
                              void* d_out, int out_size, void* d_ws, size_t ws_size,
                              hipStream_t stream) {
  (void)in_sizes; (void)n_in; (void)out_size; (void)ws_size;
  const float* visual   = (const float*)d_in[0];
  const float* pos_emb  = (const float*)d_in[1];
  const float* question = (const float*)d_in[2];
  const float* v2out_w  = (const float*)d_in[3];
  const float* v2out_b  = (const float*)d_in[4];
  const float* self_w   = (const float*)d_in[5];
  const float* self_b   = (const float*)d_in[6];
  const float* q_w      = (const float*)d_in[7];
  const float* q_b      = (const float*)d_in[8];
  const float* k_w      = (const float*)d_in[9];
  const float* k_b      = (const float*)d_in[10];
  const float* pos_w    = (const float*)d_in[11];
  const float* pos_b    = (const float*)d_in[12];
  // d_in[13]=bias_w, d_in[14]=bias_b: constant over softmax axis with adj==1 -> cancels exactly
  const float* out_w    = (const float*)d_in[15];
  const float* out_b    = (const float*)d_in[16];
  float* out = (float*)d_out;

  char* ws = (char*)d_ws;
  size_t off = 0;
  auto alloc = [&](size_t bytes) -> void* {
    off = (off + 255) & ~(size_t)255;
    void* p = ws + off;
    off += bytes;
    return p;
  };

  unsigned short* visual_bf   = (unsigned short*)alloc(18432L * 2048 * 2);
  unsigned short* question_bf = (unsigned short*)alloc(512L * 1024 * 2);
  unsigned short* v2out_wt    = (unsigned short*)alloc(1024L * 2048 * 2);
  unsigned short* self_w1t    = (unsigned short*)alloc(1024L * 1024 * 2);
  unsigned short* self_w2t    = (unsigned short*)alloc(1024L * 1024 * 2);
  unsigned short* q_wt        = (unsigned short*)alloc(1024L * 1024 * 2);
  unsigned short* k_wt        = (unsigned short*)alloc(1024L * 1024 * 2);
  unsigned short* outw_bt     = (unsigned short*)alloc(1024L * 1024 * 2);
  unsigned short* vis_bf      = (unsigned short*)alloc(18432L * 1024 * 2);
  unsigned short* self_bf     = (unsigned short*)alloc(18432L * 1024 * 2);
  unsigned short* ngf_bf      = (unsigned short*)alloc(10240L * 1024 * 2);
  unsigned short* q_bf        = (unsigned short*)alloc(18432L * 1024 * 2);
  unsigned short* k_bf        = (unsigned short*)alloc(10240L * 1024 * 2);
  unsigned short* kg_bf       = (unsigned short*)alloc(10240L * 1024 * 2);
  float*          plog        = (float*)alloc(368640L * 16 * 4);
  float*          QW          = (float*)alloc(512L * 1024 * 4);
  float*          maskp       = (float*)alloc(18432L * 4);

  // 1) converts
  k_f32_to_bf16<<<18432, 256, 0, stream>>>(visual, visual_bf, 18432L * 2048 / 8);
  k_f32_to_bf16<<<256, 256, 0, stream>>>(question, question_bf, 512L * 1024 / 8);
  // 2) weight transposes (to [n][k] bf16)
  k_transpose_bf16<<<dim3(32, 64), 256, 0, stream>>>(v2out_w, v2out_wt, 2048, 1024);
  k_transpose_bf16<<<dim3(32, 32), 256, 0, stream>>>(self_w, self_w1t, 1024, 1024);
  k_transpose_bf16<<<dim3(32, 32), 256, 0, stream>>>(self_w + 1024L * 1024, self_w2t, 1024, 1024);
  k_transpose_bf16<<<dim3(32, 32), 256, 0, stream>>>(q_w, q_wt, 1024, 1024);
  k_transpose_bf16<<<dim3(32, 32), 256, 0, stream>>>(k_w, k_wt, 1024, 1024);
  k_transpose_outw<<<dim3(2, 32, 16), 256, 0, stream>>>(out_w, outw_bt);

  // 3) vis = relu(visual @ v2out_w + b)  [bf16 only]
  k_gemm<EPI_VIS><<<dim3(8, 144), 256, 0, stream>>>(visual_bf, v2out_wt, 18432, 2048,
      v2out_b, nullptr, nullptr, nullptr, vis_bf, nullptr);
  // 4) row mask (any-nonzero of relu output)
  k_mask<<<4608, 256, 0, stream>>>(vis_bf, maskp);
  // 5) QW = question @ self_w[1024:]
  k_gemm<EPI_QW><<<dim3(8, 4), 256, 0, stream>>>(question_bf, self_w2t, 512, 1024,
      nullptr, nullptr, nullptr, QW, nullptr, nullptr);
  // 6) self_feat = vis @ self_w[:1024] + mask*QW + b   (+ gather ngf)
  k_gemm<EPI_SELF><<<dim3(8, 144), 256, 0, stream>>>(vis_bf, self_w1t, 18432, 1024,
      self_b, maskp, QW, nullptr, self_bf, ngf_bf);
  // 7) q = self_feat @ q_w + b
  k_gemm<EPI_Q><<<dim3(8, 144), 256, 0, stream>>>(self_bf, q_wt, 18432, 1024,
      q_b, nullptr, nullptr, nullptr, q_bf, nullptr);
  // 8) k = ngf @ k_w + b
  k_gemm<EPI_K><<<dim3(8, 80), 256, 0, stream>>>(ngf_bf, k_wt, 10240, 1024,
      k_b, nullptr, nullptr, nullptr, k_bf, nullptr);
  // 9) KG = ngf @ out_w (reassociated einsum: (attn@ngf)@out_w = attn@(ngf@out_w))
  k_gemm<EPI_KG><<<dim3(8, 80), 256, 0, stream>>>(ngf_bf, outw_bt, 10240, 1024,
      nullptr, nullptr, nullptr, nullptr, kg_bf, nullptr);
  // 10) pos logits
  k_poslogit<<<23040, 256, 0, stream>>>(pos_emb, pos_w, pos_b, plog);
  // 11) fused attention + neighbor + residual
  k_attn<<<512, 576, 0, stream>>>(q_bf, k_bf, kg_bf, plog, self_bf, vis_bf, out_b, out);
}